// Round 1
// baseline (577.454 us; speedup 1.0000x reference)
//
#include <hip/hip_runtime.h>
#include <math.h>

// Problem constants
#define LL    65536
#define NB    32
#define TSUB  128                 // output timesteps per thread
#define TBLK  (16 * TSUB)         // timesteps per block (16 j-chunks)
#define NTILES (LL / TBLK)        // 32 tiles along time
#define WARM  192                 // warm-up steps (alpha^192 ~ 1e-28; co-spike resync is exact)
#define NI    (NB * 16 * LL)      // elements per big output (33,554,432)

__device__ __forceinline__ double softplus_d(double x) {
  return (x > 0.0) ? (x + log1p(exp(-x))) : log1p(exp(x));
}

// Block: 256 threads = 16 channels (c16 = branch*8 + c) x 16 time-chunks (j).
// Grid: (NTILES, B). Each thread runs a serial LIF scan over WARM+TSUB steps,
// recomputing the K=8 causal conv from a sliding register window of x.
// R1: 16-step register batching so each lane's 4 float4 stores complete a
// 64B line back-to-back -> L2 write-back evicts each line once, fully dirty.
// R2: cut peak VGPR pressure (64 -> 32 array regs) to avoid scratch spill at
// the __launch_bounds__(256,4) 128-VGPR cap:
//   - sb[] removed: s == (z >= 0) exactly (z = 15*(vpre-thr); subtraction is
//     Sterbenz-exact near thr, so the sign test is identical; -0 unreachable)
//   - gb[] removed: Z and S are stored first, then the 16-lane max butterfly
//     runs IN PLACE on zb[]
__global__ __launch_bounds__(256, 4)
void snn_fused(const float* __restrict__ x,
               const float* __restrict__ wa, const float* __restrict__ wb,
               const float* __restrict__ rta, const float* __restrict__ rtb,
               const float* __restrict__ rga, const float* __restrict__ rgb,
               float* __restrict__ out)
{
  const int tid  = threadIdx.x;
  const int c16  = tid & 15;      // channel within concat order (0..7 = a, 8..15 = b)
  const int j    = tid >> 4;      // time-chunk within block
  const int tile = blockIdx.x;
  const int b    = blockIdx.y;
  const int br   = c16 >> 3;
  const int c    = c16 & 7;

  // --- per-thread constants, computed in double then rounded to f32 ---
  const float* wrow = (br ? wb : wa) + c * 8;
  double ss = 0.0;
  #pragma unroll
  for (int k = 0; k < 8; ++k) { double wv = (double)wrow[k]; ss += wv * wv; }
  double nrm = sqrt(ss); if (nrm < 1e-8) nrm = 1e-8;
  const float w0 = (float)((double)wrow[0] / nrm);
  const float w1 = (float)((double)wrow[1] / nrm);
  const float w2 = (float)((double)wrow[2] / nrm);
  const float w3 = (float)((double)wrow[3] / nrm);
  const float w4 = (float)((double)wrow[4] / nrm);
  const float w5 = (float)((double)wrow[5] / nrm);
  const float w6 = (float)((double)wrow[6] / nrm);
  const float w7 = (float)((double)wrow[7] / nrm);

  const float rt    = br ? rtb[c] : rta[c];
  const float alpha = (float)exp(-1.0 / (softplus_d((double)rt) + 1e-4));
  const float oma   = 1.0f - alpha;
  const float g     = (float)(softplus_d((double)(br ? rgb[0] : rga[0])) + 1e-4);

  const int t_out = tile * TBLK + j * TSUB;
  int t0 = t_out - WARM; if (t0 < 0) t0 = 0;   // clamped start is EXACT (v0=0 at t=0)

  const float* xrow = x + (size_t)(b * 2 + br) * LL;

  // sliding window: x[t-7..t-1] pre-scaled by X_SCALE=20
  float m7, m6, m5, m4, m3, m2, m1;
  {
    const int base = t0 - 7;
    m7 = (base + 0 >= 0) ? 20.0f * xrow[base + 0] : 0.0f;
    m6 = (base + 1 >= 0) ? 20.0f * xrow[base + 1] : 0.0f;
    m5 = (base + 2 >= 0) ? 20.0f * xrow[base + 2] : 0.0f;
    m4 = (base + 3 >= 0) ? 20.0f * xrow[base + 3] : 0.0f;
    m3 = (base + 4 >= 0) ? 20.0f * xrow[base + 4] : 0.0f;
    m2 = (base + 5 >= 0) ? 20.0f * xrow[base + 5] : 0.0f;
    m1 = (base + 6 >= 0) ? 20.0f * xrow[base + 6] : 0.0f;
  }
  float v = 0.0f;

  // one LIF step; cx = 20*x[t]; updates window + membrane state
  auto step = [&](float cx, float& Iv, float& zv) {
    float acc = m7 * w0;
    acc = fmaf(m6, w1, acc);
    acc = fmaf(m5, w2, acc);
    acc = fmaf(m4, w3, acc);
    acc = fmaf(m3, w4, acc);
    acc = fmaf(m2, w5, acc);
    acc = fmaf(m1, w6, acc);
    acc = fmaf(cx, w7, acc);
    Iv = g * acc;
    float vpre = fmaf(alpha, v, oma * Iv);
    zv = 15.0f * (vpre - 0.25f);
    v  = (vpre >= 0.25f) ? 0.0f : vpre;
    m7 = m6; m6 = m5; m5 = m4; m4 = m3; m3 = m2; m2 = m1; m1 = cx;
  };

  // --- warm-up (no stores) ---
  for (int t = t0; t < t_out; t += 4) {
    const float4 xv = *(const float4*)(xrow + t);
    float dI, dz;
    step(20.0f * xv.x, dI, dz);
    step(20.0f * xv.y, dI, dz);
    step(20.0f * xv.z, dI, dz);
    step(20.0f * xv.w, dI, dz);
  }

  float* outI = out + (size_t)(b * 16 + c16) * LL;
  float* outZ = outI + (size_t)NI;
  float* outS = outI + (size_t)2 * NI;
  float* outG = out + (size_t)3 * NI + (size_t)b * LL;

  // --- output region: 16-step batches; per batch each lane fills one full
  // 64B line per output with 4 back-to-back float4 stores ---
  for (int t = t_out; t < t_out + TSUB; t += 16) {
    float Ib[16], zb[16];
    #pragma unroll
    for (int q = 0; q < 4; ++q) {
      const float4 xv = *(const float4*)(xrow + t + 4 * q);
      step(20.0f * xv.x, Ib[4*q+0], zb[4*q+0]);
      step(20.0f * xv.y, Ib[4*q+1], zb[4*q+1]);
      step(20.0f * xv.z, Ib[4*q+2], zb[4*q+2]);
      step(20.0f * xv.w, Ib[4*q+3], zb[4*q+3]);
    }

    float4* pI = (float4*)(outI + t);
    float4* pZ = (float4*)(outZ + t);
    float4* pS = (float4*)(outS + t);
    #pragma unroll
    for (int q = 0; q < 4; ++q)
      pI[q] = make_float4(Ib[4*q+0], Ib[4*q+1], Ib[4*q+2], Ib[4*q+3]);
    #pragma unroll
    for (int q = 0; q < 4; ++q)
      pZ[q] = make_float4(zb[4*q+0], zb[4*q+1], zb[4*q+2], zb[4*q+3]);
    // s recomputed from z's sign (exact; see R2 note) -- no sb[] array
    #pragma unroll
    for (int q = 0; q < 4; ++q)
      pS[q] = make_float4(zb[4*q+0] >= 0.0f ? 1.0f : 0.0f,
                          zb[4*q+1] >= 0.0f ? 1.0f : 0.0f,
                          zb[4*q+2] >= 0.0f ? 1.0f : 0.0f,
                          zb[4*q+3] >= 0.0f ? 1.0f : 0.0f);

    // logits: max over 16 channels, xor-shuffle butterfly IN PLACE on zb
    // (zb is dead after the Z/S stores above)
    #pragma unroll
    for (int msk = 1; msk < 16; msk <<= 1) {
      #pragma unroll
      for (int q = 0; q < 16; ++q) zb[q] = fmaxf(zb[q], __shfl_xor(zb[q], msk, 16));
    }
    if (c16 == 0) {
      float4* pG = (float4*)(outG + t);
      #pragma unroll
      for (int q = 0; q < 4; ++q)
        pG[q] = make_float4(zb[4*q+0], zb[4*q+1], zb[4*q+2], zb[4*q+3]);
    }
  }
}

extern "C" void kernel_launch(void* const* d_in, const int* in_sizes, int n_in,
                              void* d_out, int out_size, void* d_ws, size_t ws_size,
                              hipStream_t stream) {
  const float* x   = (const float*)d_in[0];
  const float* wa  = (const float*)d_in[1];
  const float* wb  = (const float*)d_in[2];
  const float* rta = (const float*)d_in[3];
  const float* rtb = (const float*)d_in[4];
  const float* rga = (const float*)d_in[5];
  const float* rgb = (const float*)d_in[6];
  float* out = (float*)d_out;

  dim3 grid(NTILES, NB);
  hipLaunchKernelGGL(snn_fused, grid, dim3(256), 0, stream,
                     x, wa, wb, rta, rtb, rga, rgb, out);
}

// Round 2
// 545.035 us; speedup vs baseline: 1.0595x; 1.0595x over previous
//
#include <hip/hip_runtime.h>
#include <math.h>

// Problem constants
#define LL    65536
#define NB    32
#define TSUB  128                 // output timesteps per thread
#define TBLK  (16 * TSUB)         // timesteps per block (16 j-chunks)
#define NTILES (LL / TBLK)        // 32 tiles along time
#define WARM  192                 // warm-up steps (alpha^192 ~ 1e-28; co-spike resync is exact)
#define NI    (NB * 16 * LL)      // elements per big output (33,554,432)

__device__ __forceinline__ double softplus_d(double x) {
  return (x > 0.0) ? (x + log1p(exp(-x))) : log1p(exp(x));
}

// Block: 256 threads = 16 channels (c16 = branch*8 + c) x 16 time-chunks (j).
// Grid: (NTILES, B). Each thread runs a serial LIF scan over WARM+TSUB steps,
// recomputing the K=8 causal conv from a sliding register window of x.
// R2: sb[]/gb[] eliminated (s == (z>=0) exactly; butterfly runs in place on zb)
// R3: 32-step batching. TCC lines are 128B; the old 16-step batch left every
// line half-dirty for ~16 LIF steps while the aggregate dirty working set
// (12.6 MB/XCD) blew past the 4 MB per-XCD L2 -> partial-line evictions
// (masked 64B HBM writes or RMW fetches). Now each lane completes a full
// 128B line per output with 8 back-to-back float4 stores, so every eviction
// is a clean full-line write.
__global__ __launch_bounds__(256, 4)
void snn_fused(const float* __restrict__ x,
               const float* __restrict__ wa, const float* __restrict__ wb,
               const float* __restrict__ rta, const float* __restrict__ rtb,
               const float* __restrict__ rga, const float* __restrict__ rgb,
               float* __restrict__ out)
{
  const int tid  = threadIdx.x;
  const int c16  = tid & 15;      // channel within concat order (0..7 = a, 8..15 = b)
  const int j    = tid >> 4;      // time-chunk within block
  const int tile = blockIdx.x;
  const int b    = blockIdx.y;
  const int br   = c16 >> 3;
  const int c    = c16 & 7;

  // --- per-thread constants, computed in double then rounded to f32 ---
  const float* wrow = (br ? wb : wa) + c * 8;
  double ss = 0.0;
  #pragma unroll
  for (int k = 0; k < 8; ++k) { double wv = (double)wrow[k]; ss += wv * wv; }
  double nrm = sqrt(ss); if (nrm < 1e-8) nrm = 1e-8;
  const float w0 = (float)((double)wrow[0] / nrm);
  const float w1 = (float)((double)wrow[1] / nrm);
  const float w2 = (float)((double)wrow[2] / nrm);
  const float w3 = (float)((double)wrow[3] / nrm);
  const float w4 = (float)((double)wrow[4] / nrm);
  const float w5 = (float)((double)wrow[5] / nrm);
  const float w6 = (float)((double)wrow[6] / nrm);
  const float w7 = (float)((double)wrow[7] / nrm);

  const float rt    = br ? rtb[c] : rta[c];
  const float alpha = (float)exp(-1.0 / (softplus_d((double)rt) + 1e-4));
  const float oma   = 1.0f - alpha;
  const float g     = (float)(softplus_d((double)(br ? rgb[0] : rga[0])) + 1e-4);

  const int t_out = tile * TBLK + j * TSUB;
  int t0 = t_out - WARM; if (t0 < 0) t0 = 0;   // clamped start is EXACT (v0=0 at t=0)

  const float* xrow = x + (size_t)(b * 2 + br) * LL;

  // sliding window: x[t-7..t-1] pre-scaled by X_SCALE=20
  float m7, m6, m5, m4, m3, m2, m1;
  {
    const int base = t0 - 7;
    m7 = (base + 0 >= 0) ? 20.0f * xrow[base + 0] : 0.0f;
    m6 = (base + 1 >= 0) ? 20.0f * xrow[base + 1] : 0.0f;
    m5 = (base + 2 >= 0) ? 20.0f * xrow[base + 2] : 0.0f;
    m4 = (base + 3 >= 0) ? 20.0f * xrow[base + 3] : 0.0f;
    m3 = (base + 4 >= 0) ? 20.0f * xrow[base + 4] : 0.0f;
    m2 = (base + 5 >= 0) ? 20.0f * xrow[base + 5] : 0.0f;
    m1 = (base + 6 >= 0) ? 20.0f * xrow[base + 6] : 0.0f;
  }
  float v = 0.0f;

  // one LIF step; cx = 20*x[t]; updates window + membrane state
  auto step = [&](float cx, float& Iv, float& zv) {
    float acc = m7 * w0;
    acc = fmaf(m6, w1, acc);
    acc = fmaf(m5, w2, acc);
    acc = fmaf(m4, w3, acc);
    acc = fmaf(m3, w4, acc);
    acc = fmaf(m2, w5, acc);
    acc = fmaf(m1, w6, acc);
    acc = fmaf(cx, w7, acc);
    Iv = g * acc;
    float vpre = fmaf(alpha, v, oma * Iv);
    zv = 15.0f * (vpre - 0.25f);
    v  = (vpre >= 0.25f) ? 0.0f : vpre;
    m7 = m6; m6 = m5; m5 = m4; m4 = m3; m3 = m2; m2 = m1; m1 = cx;
  };

  // --- warm-up (no stores) ---
  for (int t = t0; t < t_out; t += 4) {
    const float4 xv = *(const float4*)(xrow + t);
    float dI, dz;
    step(20.0f * xv.x, dI, dz);
    step(20.0f * xv.y, dI, dz);
    step(20.0f * xv.z, dI, dz);
    step(20.0f * xv.w, dI, dz);
  }

  float* outI = out + (size_t)(b * 16 + c16) * LL;
  float* outZ = outI + (size_t)NI;
  float* outS = outI + (size_t)2 * NI;
  float* outG = out + (size_t)3 * NI + (size_t)b * LL;

  // --- output region: 32-step batches; per batch each lane fills one full
  // 128B TCC line per output with 8 back-to-back float4 stores ---
  for (int t = t_out; t < t_out + TSUB; t += 32) {
    float Ib[32], zb[32];
    #pragma unroll
    for (int q = 0; q < 8; ++q) {
      const float4 xv = *(const float4*)(xrow + t + 4 * q);
      step(20.0f * xv.x, Ib[4*q+0], zb[4*q+0]);
      step(20.0f * xv.y, Ib[4*q+1], zb[4*q+1]);
      step(20.0f * xv.z, Ib[4*q+2], zb[4*q+2]);
      step(20.0f * xv.w, Ib[4*q+3], zb[4*q+3]);
    }

    float4* pI = (float4*)(outI + t);
    float4* pZ = (float4*)(outZ + t);
    float4* pS = (float4*)(outS + t);
    #pragma unroll
    for (int q = 0; q < 8; ++q)
      pI[q] = make_float4(Ib[4*q+0], Ib[4*q+1], Ib[4*q+2], Ib[4*q+3]);
    #pragma unroll
    for (int q = 0; q < 8; ++q)
      pZ[q] = make_float4(zb[4*q+0], zb[4*q+1], zb[4*q+2], zb[4*q+3]);
    // s recomputed from z's sign (exact; see R2 note) -- no sb[] array
    #pragma unroll
    for (int q = 0; q < 8; ++q)
      pS[q] = make_float4(zb[4*q+0] >= 0.0f ? 1.0f : 0.0f,
                          zb[4*q+1] >= 0.0f ? 1.0f : 0.0f,
                          zb[4*q+2] >= 0.0f ? 1.0f : 0.0f,
                          zb[4*q+3] >= 0.0f ? 1.0f : 0.0f);

    // logits: max over 16 channels, xor-shuffle butterfly IN PLACE on zb
    // (zb is dead after the Z/S stores above)
    #pragma unroll
    for (int msk = 1; msk < 16; msk <<= 1) {
      #pragma unroll
      for (int q = 0; q < 32; ++q) zb[q] = fmaxf(zb[q], __shfl_xor(zb[q], msk, 16));
    }
    if (c16 == 0) {
      float4* pG = (float4*)(outG + t);
      #pragma unroll
      for (int q = 0; q < 8; ++q)
        pG[q] = make_float4(zb[4*q+0], zb[4*q+1], zb[4*q+2], zb[4*q+3]);
    }
  }
}

extern "C" void kernel_launch(void* const* d_in, const int* in_sizes, int n_in,
                              void* d_out, int out_size, void* d_ws, size_t ws_size,
                              hipStream_t stream) {
  const float* x   = (const float*)d_in[0];
  const float* wa  = (const float*)d_in[1];
  const float* wb  = (const float*)d_in[2];
  const float* rta = (const float*)d_in[3];
  const float* rtb = (const float*)d_in[4];
  const float* rga = (const float*)d_in[5];
  const float* rgb = (const float*)d_in[6];
  float* out = (float*)d_out;

  dim3 grid(NTILES, NB);
  hipLaunchKernelGGL(snn_fused, grid, dim3(256), 0, stream,
                     x, wa, wb, rta, rtb, rga, rgb, out);
}

// Round 3
// 456.805 us; speedup vs baseline: 1.2641x; 1.1931x over previous
//
#include <hip/hip_runtime.h>
#include <math.h>

// Problem constants
#define LL    65536
#define NB    32
#define TSUB  128                 // output timesteps per thread
#define TBLK  (16 * TSUB)         // timesteps per block (16 j-chunks)
#define NTILES (LL / TBLK)        // 32 tiles along time
#define WARM  192                 // warm-up steps (alpha^192 ~ 1e-28; co-spike resync is exact)
#define NI    (NB * 16 * LL)      // elements per big output (33,554,432)

__device__ __forceinline__ double softplus_d(double x) {
  return (x > 0.0) ? (x + log1p(exp(-x))) : log1p(exp(x));
}

// Block: 256 threads = 16 channels (c16 = branch*8 + c) x 16 time-chunks (j).
// Grid: (NTILES, B). Each thread runs a serial LIF scan over WARM+TSUB steps,
// recomputing the K=8 causal conv from a sliding register window of x.
// R2: sb[]/gb[] eliminated (s == (z>=0) exactly; butterfly runs in place on zb)
// R3: 32-step batching (full 128B line per lane per output per batch).
// R4: wave-local LDS transpose of the store pattern. The compute mapping puts
// adjacent lanes on adjacent CHANNELS (stride LL floats), so a direct
// global_store_dwordx4 scatters to 64 distinct 128B lines per instruction
// (8x the TA/L2 transactions of a coalesced store; every L2 write a 16B
// masked partial-line access). Each wave now stages its batch into LDS
// ([64][36] floats, padded -> minimal 8-phase b128 banking) and reads back
// remapped so each store instruction covers 8 FULL 128B lines (8 lanes per
// contiguous 128B segment), matching the access pattern that the poison
// fill demonstrates runs at 5.7 TB/s. Wave-synchronous: no barriers.
__global__ __launch_bounds__(256, 4)
void snn_fused(const float* __restrict__ x,
               const float* __restrict__ wa, const float* __restrict__ wb,
               const float* __restrict__ rta, const float* __restrict__ rtb,
               const float* __restrict__ rga, const float* __restrict__ rgb,
               float* __restrict__ out)
{
  const int tid  = threadIdx.x;
  const int c16  = tid & 15;      // channel within concat order (0..7 = a, 8..15 = b)
  const int j    = tid >> 4;      // time-chunk within block
  const int tile = blockIdx.x;
  const int b    = blockIdx.y;
  const int br   = c16 >> 3;
  const int c    = c16 & 7;

  // --- per-thread constants, computed in double then rounded to f32 ---
  const float* wrow = (br ? wb : wa) + c * 8;
  double ss = 0.0;
  #pragma unroll
  for (int k = 0; k < 8; ++k) { double wv = (double)wrow[k]; ss += wv * wv; }
  double nrm = sqrt(ss); if (nrm < 1e-8) nrm = 1e-8;
  const float w0 = (float)((double)wrow[0] / nrm);
  const float w1 = (float)((double)wrow[1] / nrm);
  const float w2 = (float)((double)wrow[2] / nrm);
  const float w3 = (float)((double)wrow[3] / nrm);
  const float w4 = (float)((double)wrow[4] / nrm);
  const float w5 = (float)((double)wrow[5] / nrm);
  const float w6 = (float)((double)wrow[6] / nrm);
  const float w7 = (float)((double)wrow[7] / nrm);

  const float rt    = br ? rtb[c] : rta[c];
  const float alpha = (float)exp(-1.0 / (softplus_d((double)rt) + 1e-4));
  const float oma   = 1.0f - alpha;
  const float g     = (float)(softplus_d((double)(br ? rgb[0] : rga[0])) + 1e-4);

  const int t_out = tile * TBLK + j * TSUB;
  int t0 = t_out - WARM; if (t0 < 0) t0 = 0;   // clamped start is EXACT (v0=0 at t=0)

  const float* xrow = x + (size_t)(b * 2 + br) * LL;

  // sliding window: x[t-7..t-1] pre-scaled by X_SCALE=20
  float m7, m6, m5, m4, m3, m2, m1;
  {
    const int base = t0 - 7;
    m7 = (base + 0 >= 0) ? 20.0f * xrow[base + 0] : 0.0f;
    m6 = (base + 1 >= 0) ? 20.0f * xrow[base + 1] : 0.0f;
    m5 = (base + 2 >= 0) ? 20.0f * xrow[base + 2] : 0.0f;
    m4 = (base + 3 >= 0) ? 20.0f * xrow[base + 3] : 0.0f;
    m3 = (base + 4 >= 0) ? 20.0f * xrow[base + 4] : 0.0f;
    m2 = (base + 5 >= 0) ? 20.0f * xrow[base + 5] : 0.0f;
    m1 = (base + 6 >= 0) ? 20.0f * xrow[base + 6] : 0.0f;
  }
  float v = 0.0f;

  // one LIF step; cx = 20*x[t]; updates window + membrane state
  auto step = [&](float cx, float& Iv, float& zv) {
    float acc = m7 * w0;
    acc = fmaf(m6, w1, acc);
    acc = fmaf(m5, w2, acc);
    acc = fmaf(m4, w3, acc);
    acc = fmaf(m3, w4, acc);
    acc = fmaf(m2, w5, acc);
    acc = fmaf(m1, w6, acc);
    acc = fmaf(cx, w7, acc);
    Iv = g * acc;
    float vpre = fmaf(alpha, v, oma * Iv);
    zv = 15.0f * (vpre - 0.25f);
    v  = (vpre >= 0.25f) ? 0.0f : vpre;
    m7 = m6; m6 = m5; m5 = m4; m4 = m3; m3 = m2; m2 = m1; m1 = cx;
  };

  // --- warm-up (no stores) ---
  for (int t = t0; t < t_out; t += 4) {
    const float4 xv = *(const float4*)(xrow + t);
    float dI, dz;
    step(20.0f * xv.x, dI, dz);
    step(20.0f * xv.y, dI, dz);
    step(20.0f * xv.z, dI, dz);
    step(20.0f * xv.w, dI, dz);
  }

  // --- R4 transpose-store setup ---
  // Per-wave staging: [64 rows][36 floats] (pad 32->36 keeps 16B alignment and
  // gives minimal 8-phase banking for both the row-write and the remapped read).
  __shared__ __align__(16) float xp[4][64 * 36];
  const int lane = tid & 63;
  const int wv   = tid >> 6;
  const int hi   = lane >> 3;     // output-lane group: which segment
  const int lo   = lane & 7;      // 16B chunk within the 128B segment
  float*       lrow = &xp[wv][lane * 36];          // this lane's write row
  const float* lrd  = &xp[wv][hi * 288 + 4 * lo];  // read base: rows 8*hi+r
  // Store instruction r covers owner-lanes o = 8*hi + r (this wave), i.e.
  // channel c_o = 8*(hi&1) + r, chunk jj_o = hi>>1  (j_o = wv*4 + jj_o).
  // Global element index for this lane at store r: gbase + r*LL (+ batch off).
  const int gbase = (b * 16 + 8 * (hi & 1)) * LL
                  + tile * TBLK + (wv * 4 + (hi >> 1)) * TSUB + 4 * lo;

  float* outG = out + (size_t)3 * NI + (size_t)b * LL;

  // --- output region: 32-step batches ---
  for (int t = t_out; t < t_out + TSUB; t += 32) {
    const int bb = t - t_out + (gbase - 0);  // gbase + batch offset (element idx)
    float Ib[32], zb[32];
    #pragma unroll
    for (int q = 0; q < 8; ++q) {
      const float4 xv = *(const float4*)(xrow + t + 4 * q);
      step(20.0f * xv.x, Ib[4*q+0], zb[4*q+0]);
      step(20.0f * xv.y, Ib[4*q+1], zb[4*q+1]);
      step(20.0f * xv.z, Ib[4*q+2], zb[4*q+2]);
      step(20.0f * xv.w, Ib[4*q+3], zb[4*q+3]);
    }

    // ---- I: stage to LDS, read back remapped, coalesced store ----
    #pragma unroll
    for (int q = 0; q < 8; ++q)
      *(float4*)(lrow + 4 * q) = make_float4(Ib[4*q+0], Ib[4*q+1], Ib[4*q+2], Ib[4*q+3]);
    #pragma unroll
    for (int r = 0; r < 8; ++r) {
      const float4 v4 = *(const float4*)(lrd + 36 * r);
      *(float4*)(out + (size_t)(bb + r * LL)) = v4;
    }

    // ---- z ----
    #pragma unroll
    for (int q = 0; q < 8; ++q)
      *(float4*)(lrow + 4 * q) = make_float4(zb[4*q+0], zb[4*q+1], zb[4*q+2], zb[4*q+3]);
    #pragma unroll
    for (int r = 0; r < 8; ++r) {
      const float4 v4 = *(const float4*)(lrd + 36 * r);
      *(float4*)(out + (size_t)NI + (size_t)(bb + r * LL)) = v4;
    }

    // ---- s: recomputed from z's sign (exact; see R2 note) ----
    #pragma unroll
    for (int q = 0; q < 8; ++q)
      *(float4*)(lrow + 4 * q) = make_float4(zb[4*q+0] >= 0.0f ? 1.0f : 0.0f,
                                             zb[4*q+1] >= 0.0f ? 1.0f : 0.0f,
                                             zb[4*q+2] >= 0.0f ? 1.0f : 0.0f,
                                             zb[4*q+3] >= 0.0f ? 1.0f : 0.0f);
    #pragma unroll
    for (int r = 0; r < 8; ++r) {
      const float4 v4 = *(const float4*)(lrd + 36 * r);
      *(float4*)(out + (size_t)2 * NI + (size_t)(bb + r * LL)) = v4;
    }

    // logits: max over 16 channels, xor-shuffle butterfly IN PLACE on zb
    // (zb is dead after the s staging above)
    #pragma unroll
    for (int msk = 1; msk < 16; msk <<= 1) {
      #pragma unroll
      for (int q = 0; q < 32; ++q) zb[q] = fmaxf(zb[q], __shfl_xor(zb[q], msk, 16));
    }
    if (c16 == 0) {
      float4* pG = (float4*)(outG + t);
      #pragma unroll
      for (int q = 0; q < 8; ++q)
        pG[q] = make_float4(zb[4*q+0], zb[4*q+1], zb[4*q+2], zb[4*q+3]);
    }
  }
}

extern "C" void kernel_launch(void* const* d_in, const int* in_sizes, int n_in,
                              void* d_out, int out_size, void* d_ws, size_t ws_size,
                              hipStream_t stream) {
  const float* x   = (const float*)d_in[0];
  const float* wa  = (const float*)d_in[1];
  const float* wb  = (const float*)d_in[2];
  const float* rta = (const float*)d_in[3];
  const float* rtb = (const float*)d_in[4];
  const float* rga = (const float*)d_in[5];
  const float* rgb = (const float*)d_in[6];
  float* out = (float*)d_out;

  dim3 grid(NTILES, NB);
  hipLaunchKernelGGL(snn_fused, grid, dim3(256), 0, stream,
                     x, wa, wb, rta, rtb, rga, rgb, out);
}

// Round 4
// 455.519 us; speedup vs baseline: 1.2677x; 1.0028x over previous
//
#include <hip/hip_runtime.h>
#include <math.h>

// Problem constants
#define LL    65536
#define NB    32
#define TSUB  128                 // output timesteps per thread
#define TBLK  (16 * TSUB)         // timesteps per block (16 j-chunks)
#define NTILES (LL / TBLK)        // 32 tiles along time
#define WARM  192                 // warm-up steps (alpha^192 ~ 1e-28; co-spike resync is exact)
#define NI    (NB * 16 * LL)      // elements per big output (33,554,432)

__device__ __forceinline__ double softplus_d(double x) {
  return (x > 0.0) ? (x + log1p(exp(-x))) : log1p(exp(x));
}

// DPP row-rotate max: y = max(y, rotate_within_row16(y, N)).
// Rotation all-reduce over s=1,2,4,8 gives every lane the 16-lane max.
// VALU-only: replaces the ds_bpermute butterfly (DS-pipe) entirely.
#define ROTMAX(x, CTRL)                                                        \
  (x) = fmaxf((x), __int_as_float(__builtin_amdgcn_update_dpp(                 \
                 __float_as_int(x), __float_as_int(x), (CTRL), 0xf, 0xf, true)))

// Block: 256 threads = 16 channels (c16 = branch*8 + c) x 16 time-chunks (j).
// Grid: (NTILES, B). Each thread runs a serial LIF scan over WARM+TSUB steps,
// recomputing the K=8 causal conv from a sliding register window of x.
// R2: sb[]/gb[] eliminated (s == (z>=0) exactly)
// R3: 32-step batching (full 128B line per lane per output per batch).
// R4: wave-local LDS transpose -> every global store instruction covers 8
//     full 128B lines (fill-like pattern, 5.7 TB/s capable).
// R5: DS-pipe decongestion. rocprof model showed ~47us/CU of DS serialization:
//     the __shfl_xor butterfly lowered to 128 ds_bpermute per batch (more DS
//     work than staging) and s had its own 16-instr staging pass.
//     (a) logits max now VALU-only via DPP row_ror rotation all-reduce;
//     (b) s recomputed from the z LDS read-back (third staging pass deleted).
//     DS instrs/batch/wave: 176 -> 32.
__global__ __launch_bounds__(256, 4)
void snn_fused(const float* __restrict__ x,
               const float* __restrict__ wa, const float* __restrict__ wb,
               const float* __restrict__ rta, const float* __restrict__ rtb,
               const float* __restrict__ rga, const float* __restrict__ rgb,
               float* __restrict__ out)
{
  const int tid  = threadIdx.x;
  const int c16  = tid & 15;      // channel within concat order (0..7 = a, 8..15 = b)
  const int j    = tid >> 4;      // time-chunk within block
  const int tile = blockIdx.x;
  const int b    = blockIdx.y;
  const int br   = c16 >> 3;
  const int c    = c16 & 7;

  // --- per-thread constants, computed in double then rounded to f32 ---
  const float* wrow = (br ? wb : wa) + c * 8;
  double ss = 0.0;
  #pragma unroll
  for (int k = 0; k < 8; ++k) { double wv = (double)wrow[k]; ss += wv * wv; }
  double nrm = sqrt(ss); if (nrm < 1e-8) nrm = 1e-8;
  const float w0 = (float)((double)wrow[0] / nrm);
  const float w1 = (float)((double)wrow[1] / nrm);
  const float w2 = (float)((double)wrow[2] / nrm);
  const float w3 = (float)((double)wrow[3] / nrm);
  const float w4 = (float)((double)wrow[4] / nrm);
  const float w5 = (float)((double)wrow[5] / nrm);
  const float w6 = (float)((double)wrow[6] / nrm);
  const float w7 = (float)((double)wrow[7] / nrm);

  const float rt    = br ? rtb[c] : rta[c];
  const float alpha = (float)exp(-1.0 / (softplus_d((double)rt) + 1e-4));
  const float oma   = 1.0f - alpha;
  const float g     = (float)(softplus_d((double)(br ? rgb[0] : rga[0])) + 1e-4);

  const int t_out = tile * TBLK + j * TSUB;
  int t0 = t_out - WARM; if (t0 < 0) t0 = 0;   // clamped start is EXACT (v0=0 at t=0)

  const float* xrow = x + (size_t)(b * 2 + br) * LL;

  // sliding window: x[t-7..t-1] pre-scaled by X_SCALE=20
  float m7, m6, m5, m4, m3, m2, m1;
  {
    const int base = t0 - 7;
    m7 = (base + 0 >= 0) ? 20.0f * xrow[base + 0] : 0.0f;
    m6 = (base + 1 >= 0) ? 20.0f * xrow[base + 1] : 0.0f;
    m5 = (base + 2 >= 0) ? 20.0f * xrow[base + 2] : 0.0f;
    m4 = (base + 3 >= 0) ? 20.0f * xrow[base + 3] : 0.0f;
    m3 = (base + 4 >= 0) ? 20.0f * xrow[base + 4] : 0.0f;
    m2 = (base + 5 >= 0) ? 20.0f * xrow[base + 5] : 0.0f;
    m1 = (base + 6 >= 0) ? 20.0f * xrow[base + 6] : 0.0f;
  }
  float v = 0.0f;

  // one LIF step; cx = 20*x[t]; updates window + membrane state
  auto step = [&](float cx, float& Iv, float& zv) {
    float acc = m7 * w0;
    acc = fmaf(m6, w1, acc);
    acc = fmaf(m5, w2, acc);
    acc = fmaf(m4, w3, acc);
    acc = fmaf(m3, w4, acc);
    acc = fmaf(m2, w5, acc);
    acc = fmaf(m1, w6, acc);
    acc = fmaf(cx, w7, acc);
    Iv = g * acc;
    float vpre = fmaf(alpha, v, oma * Iv);
    zv = 15.0f * (vpre - 0.25f);
    v  = (vpre >= 0.25f) ? 0.0f : vpre;
    m7 = m6; m6 = m5; m5 = m4; m4 = m3; m3 = m2; m2 = m1; m1 = cx;
  };

  // --- warm-up (no stores) ---
  for (int t = t0; t < t_out; t += 4) {
    const float4 xv = *(const float4*)(xrow + t);
    float dI, dz;
    step(20.0f * xv.x, dI, dz);
    step(20.0f * xv.y, dI, dz);
    step(20.0f * xv.z, dI, dz);
    step(20.0f * xv.w, dI, dz);
  }

  // --- R4 transpose-store setup ---
  // Per-wave staging: [64 rows][36 floats] (pad 32->36 keeps 16B alignment and
  // phase-conflict-minimal banking for both row-write and remapped read).
  __shared__ __align__(16) float xp[4][64 * 36];
  const int lane = tid & 63;
  const int wv   = tid >> 6;
  const int hi   = lane >> 3;     // output-lane group: which segment
  const int lo   = lane & 7;      // 16B chunk within the 128B segment
  float*       lrow = &xp[wv][lane * 36];          // this lane's write row
  const float* lrd  = &xp[wv][hi * 288 + 4 * lo];  // read base: rows 8*hi+r
  // Store instruction r covers owner-lanes o = 8*hi + r (this wave), i.e.
  // channel c_o = 8*(hi&1) + r, chunk jj_o = hi>>1  (j_o = wv*4 + jj_o).
  const int gbase = (b * 16 + 8 * (hi & 1)) * LL
                  + tile * TBLK + (wv * 4 + (hi >> 1)) * TSUB + 4 * lo;

  float* outG = out + (size_t)3 * NI + (size_t)b * LL;

  // --- output region: 32-step batches ---
  for (int t = t_out; t < t_out + TSUB; t += 32) {
    const int bb = t - t_out + gbase;
    float Ib[32], zb[32];
    #pragma unroll
    for (int q = 0; q < 8; ++q) {
      const float4 xv = *(const float4*)(xrow + t + 4 * q);
      step(20.0f * xv.x, Ib[4*q+0], zb[4*q+0]);
      step(20.0f * xv.y, Ib[4*q+1], zb[4*q+1]);
      step(20.0f * xv.z, Ib[4*q+2], zb[4*q+2]);
      step(20.0f * xv.w, Ib[4*q+3], zb[4*q+3]);
    }

    // ---- I: stage to LDS, read back remapped, coalesced store ----
    #pragma unroll
    for (int q = 0; q < 8; ++q)
      *(float4*)(lrow + 4 * q) = make_float4(Ib[4*q+0], Ib[4*q+1], Ib[4*q+2], Ib[4*q+3]);
    #pragma unroll
    for (int r = 0; r < 8; ++r) {
      const float4 v4 = *(const float4*)(lrd + 36 * r);
      *(float4*)(out + (size_t)(bb + r * LL)) = v4;
    }

    // ---- z: stage once; store z AND s from the same read-back ----
    // (s == (z>=0) exactly; LDS round-trip is bit-preserving)
    #pragma unroll
    for (int q = 0; q < 8; ++q)
      *(float4*)(lrow + 4 * q) = make_float4(zb[4*q+0], zb[4*q+1], zb[4*q+2], zb[4*q+3]);
    #pragma unroll
    for (int r = 0; r < 8; ++r) {
      const float4 v4 = *(const float4*)(lrd + 36 * r);
      *(float4*)(out + (size_t)NI + (size_t)(bb + r * LL)) = v4;
      *(float4*)(out + (size_t)2 * NI + (size_t)(bb + r * LL)) =
        make_float4(v4.x >= 0.0f ? 1.0f : 0.0f,
                    v4.y >= 0.0f ? 1.0f : 0.0f,
                    v4.z >= 0.0f ? 1.0f : 0.0f,
                    v4.w >= 0.0f ? 1.0f : 0.0f);
    }

    // ---- logits: 16-lane max all-reduce, VALU-only (DPP row_ror) ----
    // zb register values are dead after the staging writes above; reduce
    // in place. row_ror rotates within rows of 16 = exactly our c16 groups.
    #pragma unroll
    for (int q = 0; q < 32; ++q) {
      ROTMAX(zb[q], 0x121);   // ror 1
      ROTMAX(zb[q], 0x122);   // ror 2
      ROTMAX(zb[q], 0x124);   // ror 4
      ROTMAX(zb[q], 0x128);   // ror 8
    }
    if (c16 == 0) {
      float4* pG = (float4*)(outG + t);
      #pragma unroll
      for (int q = 0; q < 8; ++q)
        pG[q] = make_float4(zb[4*q+0], zb[4*q+1], zb[4*q+2], zb[4*q+3]);
    }
  }
}

extern "C" void kernel_launch(void* const* d_in, const int* in_sizes, int n_in,
                              void* d_out, int out_size, void* d_ws, size_t ws_size,
                              hipStream_t stream) {
  const float* x   = (const float*)d_in[0];
  const float* wa  = (const float*)d_in[1];
  const float* wb  = (const float*)d_in[2];
  const float* rta = (const float*)d_in[3];
  const float* rtb = (const float*)d_in[4];
  const float* rga = (const float*)d_in[5];
  const float* rgb = (const float*)d_in[6];
  float* out = (float*)d_out;

  dim3 grid(NTILES, NB);
  hipLaunchKernelGGL(snn_fused, grid, dim3(256), 0, stream,
                     x, wa, wb, rta, rtb, rga, rgb, out);
}

// Round 6
// 453.325 us; speedup vs baseline: 1.2738x; 1.0048x over previous
//
#include <hip/hip_runtime.h>
#include <math.h>

// Problem constants
#define LL    65536
#define NB    32
#define TSUB  128                 // output timesteps per thread
#define TBLK  (16 * TSUB)         // timesteps per block (16 j-chunks)
#define NTILES (LL / TBLK)        // 32 tiles along time
#define WARM  192                 // warm-up steps (alpha^192 ~ 1e-28; co-spike resync is exact)
#define NI    (NB * 16 * LL)      // elements per big output (33,554,432)

// Native clang vector type: __builtin_nontemporal_store rejects HIP's
// float4 (a HIP_vector_type class); ext_vector_type is layout-identical.
typedef float f32x4 __attribute__((ext_vector_type(4)));

__device__ __forceinline__ double softplus_d(double x) {
  return (x > 0.0) ? (x + log1p(exp(-x))) : log1p(exp(x));
}

// DPP row-rotate max: y = max(y, rotate_within_row16(y, N)).
// Rotation all-reduce over s=1,2,4,8 gives every lane the 16-lane max.
#define ROTMAX(x, CTRL)                                                        \
  (x) = fmaxf((x), __int_as_float(__builtin_amdgcn_update_dpp(                 \
                 __float_as_int(x), __float_as_int(x), (CTRL), 0xf, 0xf, true)))

// Block: 256 threads = 16 channels (c16 = branch*8 + c) x 16 time-chunks (j).
// Grid: (NTILES, B). Each thread runs a serial LIF scan over WARM+TSUB steps,
// recomputing the K=8 causal conv from a sliding register window of x.
// R2: sb[]/gb[] eliminated (s == (z>=0) exactly)
// R3: 32-step batching (full 128B line per lane per output per batch).
// R4: wave-local LDS transpose -> every global store instruction covers 8
//     full 128B lines (fill-like pattern).
// R5: DS decongestion (DPP logit max; s from z read-back). NEUTRAL -> DS
//     pipe was latency-hidden, not critical.
// R6: NONTEMPORAL output stores (retry w/ ext_vector_type). Kernel effective
//     write BW is ~2.4 TB/s vs the fill's 5.7 TB/s on the same path; the
//     mechanism predicting a clean 2x is write-allocate RMW: L2/MALL fetches
//     each 128B line from HBM on store miss before overwriting it. Outputs
//     are write-once streams nothing re-reads; the nt bit skips allocation.
__global__ __launch_bounds__(256, 4)
void snn_fused(const float* __restrict__ x,
               const float* __restrict__ wa, const float* __restrict__ wb,
               const float* __restrict__ rta, const float* __restrict__ rtb,
               const float* __restrict__ rga, const float* __restrict__ rgb,
               float* __restrict__ out)
{
  const int tid  = threadIdx.x;
  const int c16  = tid & 15;      // channel within concat order (0..7 = a, 8..15 = b)
  const int j    = tid >> 4;      // time-chunk within block
  const int tile = blockIdx.x;
  const int b    = blockIdx.y;
  const int br   = c16 >> 3;
  const int c    = c16 & 7;

  // --- per-thread constants, computed in double then rounded to f32 ---
  const float* wrow = (br ? wb : wa) + c * 8;
  double ss = 0.0;
  #pragma unroll
  for (int k = 0; k < 8; ++k) { double wv = (double)wrow[k]; ss += wv * wv; }
  double nrm = sqrt(ss); if (nrm < 1e-8) nrm = 1e-8;
  const float w0 = (float)((double)wrow[0] / nrm);
  const float w1 = (float)((double)wrow[1] / nrm);
  const float w2 = (float)((double)wrow[2] / nrm);
  const float w3 = (float)((double)wrow[3] / nrm);
  const float w4 = (float)((double)wrow[4] / nrm);
  const float w5 = (float)((double)wrow[5] / nrm);
  const float w6 = (float)((double)wrow[6] / nrm);
  const float w7 = (float)((double)wrow[7] / nrm);

  const float rt    = br ? rtb[c] : rta[c];
  const float alpha = (float)exp(-1.0 / (softplus_d((double)rt) + 1e-4));
  const float oma   = 1.0f - alpha;
  const float g     = (float)(softplus_d((double)(br ? rgb[0] : rga[0])) + 1e-4);

  const int t_out = tile * TBLK + j * TSUB;
  int t0 = t_out - WARM; if (t0 < 0) t0 = 0;   // clamped start is EXACT (v0=0 at t=0)

  const float* xrow = x + (size_t)(b * 2 + br) * LL;

  // sliding window: x[t-7..t-1] pre-scaled by X_SCALE=20
  float m7, m6, m5, m4, m3, m2, m1;
  {
    const int base = t0 - 7;
    m7 = (base + 0 >= 0) ? 20.0f * xrow[base + 0] : 0.0f;
    m6 = (base + 1 >= 0) ? 20.0f * xrow[base + 1] : 0.0f;
    m5 = (base + 2 >= 0) ? 20.0f * xrow[base + 2] : 0.0f;
    m4 = (base + 3 >= 0) ? 20.0f * xrow[base + 3] : 0.0f;
    m3 = (base + 4 >= 0) ? 20.0f * xrow[base + 4] : 0.0f;
    m2 = (base + 5 >= 0) ? 20.0f * xrow[base + 5] : 0.0f;
    m1 = (base + 6 >= 0) ? 20.0f * xrow[base + 6] : 0.0f;
  }
  float v = 0.0f;

  // one LIF step; cx = 20*x[t]; updates window + membrane state
  auto step = [&](float cx, float& Iv, float& zv) {
    float acc = m7 * w0;
    acc = fmaf(m6, w1, acc);
    acc = fmaf(m5, w2, acc);
    acc = fmaf(m4, w3, acc);
    acc = fmaf(m3, w4, acc);
    acc = fmaf(m2, w5, acc);
    acc = fmaf(m1, w6, acc);
    acc = fmaf(cx, w7, acc);
    Iv = g * acc;
    float vpre = fmaf(alpha, v, oma * Iv);
    zv = 15.0f * (vpre - 0.25f);
    v  = (vpre >= 0.25f) ? 0.0f : vpre;
    m7 = m6; m6 = m5; m5 = m4; m4 = m3; m3 = m2; m2 = m1; m1 = cx;
  };

  // --- warm-up (no stores) ---
  for (int t = t0; t < t_out; t += 4) {
    const float4 xv = *(const float4*)(xrow + t);
    float dI, dz;
    step(20.0f * xv.x, dI, dz);
    step(20.0f * xv.y, dI, dz);
    step(20.0f * xv.z, dI, dz);
    step(20.0f * xv.w, dI, dz);
  }

  // --- R4 transpose-store setup ---
  __shared__ __align__(16) float xp[4][64 * 36];
  const int lane = tid & 63;
  const int wv   = tid >> 6;
  const int hi   = lane >> 3;     // output-lane group: which segment
  const int lo   = lane & 7;      // 16B chunk within the 128B segment
  float*       lrow = &xp[wv][lane * 36];          // this lane's write row
  const float* lrd  = &xp[wv][hi * 288 + 4 * lo];  // read base: rows 8*hi+r
  const int gbase = (b * 16 + 8 * (hi & 1)) * LL
                  + tile * TBLK + (wv * 4 + (hi >> 1)) * TSUB + 4 * lo;

  float* outG = out + (size_t)3 * NI + (size_t)b * LL;

  // --- output region: 32-step batches ---
  for (int t = t_out; t < t_out + TSUB; t += 32) {
    const int bb = t - t_out + gbase;
    float Ib[32], zb[32];
    #pragma unroll
    for (int q = 0; q < 8; ++q) {
      const float4 xv = *(const float4*)(xrow + t + 4 * q);
      step(20.0f * xv.x, Ib[4*q+0], zb[4*q+0]);
      step(20.0f * xv.y, Ib[4*q+1], zb[4*q+1]);
      step(20.0f * xv.z, Ib[4*q+2], zb[4*q+2]);
      step(20.0f * xv.w, Ib[4*q+3], zb[4*q+3]);
    }

    // ---- I: stage to LDS, read back remapped, nontemporal coalesced store ----
    #pragma unroll
    for (int q = 0; q < 8; ++q)
      *(float4*)(lrow + 4 * q) = make_float4(Ib[4*q+0], Ib[4*q+1], Ib[4*q+2], Ib[4*q+3]);
    #pragma unroll
    for (int r = 0; r < 8; ++r) {
      const f32x4 v4 = *(const f32x4*)(lrd + 36 * r);
      __builtin_nontemporal_store(v4, (f32x4*)(out + (size_t)(bb + r * LL)));
    }

    // ---- z: stage once; store z AND s from the same read-back ----
    // (s == (z>=0) exactly; LDS round-trip is bit-preserving)
    #pragma unroll
    for (int q = 0; q < 8; ++q)
      *(float4*)(lrow + 4 * q) = make_float4(zb[4*q+0], zb[4*q+1], zb[4*q+2], zb[4*q+3]);
    #pragma unroll
    for (int r = 0; r < 8; ++r) {
      const f32x4 v4 = *(const f32x4*)(lrd + 36 * r);
      __builtin_nontemporal_store(v4, (f32x4*)(out + (size_t)NI + (size_t)(bb + r * LL)));
      f32x4 s4;
      s4.x = v4.x >= 0.0f ? 1.0f : 0.0f;
      s4.y = v4.y >= 0.0f ? 1.0f : 0.0f;
      s4.z = v4.z >= 0.0f ? 1.0f : 0.0f;
      s4.w = v4.w >= 0.0f ? 1.0f : 0.0f;
      __builtin_nontemporal_store(s4, (f32x4*)(out + (size_t)2 * NI + (size_t)(bb + r * LL)));
    }

    // ---- logits: 16-lane max all-reduce, VALU-only (DPP row_ror) ----
    #pragma unroll
    for (int q = 0; q < 32; ++q) {
      ROTMAX(zb[q], 0x121);   // ror 1
      ROTMAX(zb[q], 0x122);   // ror 2
      ROTMAX(zb[q], 0x124);   // ror 4
      ROTMAX(zb[q], 0x128);   // ror 8
    }
    if (c16 == 0) {
      #pragma unroll
      for (int q = 0; q < 8; ++q) {
        f32x4 g4;
        g4.x = zb[4*q+0]; g4.y = zb[4*q+1]; g4.z = zb[4*q+2]; g4.w = zb[4*q+3];
        __builtin_nontemporal_store(g4, (f32x4*)(outG + t + 4 * q));
      }
    }
  }
}

extern "C" void kernel_launch(void* const* d_in, const int* in_sizes, int n_in,
                              void* d_out, int out_size, void* d_ws, size_t ws_size,
                              hipStream_t stream) {
  const float* x   = (const float*)d_in[0];
  const float* wa  = (const float*)d_in[1];
  const float* wb  = (const float*)d_in[2];
  const float* rta = (const float*)d_in[3];
  const float* rtb = (const float*)d_in[4];
  const float* rga = (const float*)d_in[5];
  const float* rgb = (const float*)d_in[6];
  float* out = (float*)d_out;

  dim3 grid(NTILES, NB);
  hipLaunchKernelGGL(snn_fused, grid, dim3(256), 0, stream,
                     x, wa, wb, rta, rtb, rga, rgb, out);
}